// Round 5
// baseline (987.306 us; speedup 1.0000x reference)
//
#include <hip/hip_runtime.h>
#include <hip/hip_bf16.h>
#include <math.h>

// CerberusSemanticIDBranch — fused prototype-softmax-affinity kernel for MI355X.
//
// out[r,g,:] = (e_g @ M'_g) / sum(e_g),  e_k = exp(l_k - max_g),
// l_k = (x_r . Pn_k) / ((||x_r||+1e-6) * tau),  Pn_k = P_k/(||P_k||+1e-6),
// M'_g = A_g @ P_g / (rowsum(A_g)+1e-6)   (rowsum(A) is constant per group).
//
// Round 5: BOTH matmuls on bf16 MFMA. Phase 1 (x @ Pn^T) as round 4.
// Phase 2: out_tile[64x2560] = C[64x128] @ Btilde[128x2560], where Btilde
// (mptb) is block-diagonal bf16: group g's M' rows at k in [GB,GB+GK), zeros
// elsewhere (zeros in B mask cross-group terms, A needs no masking). Dead
// K-steps skipped via per-group kstep tables. Stores straight from C-frags:
// 4 dword stores/tile = 4x64B segments (rows are 10KB apart -> that's the
// coalescing optimum). Kernel is HBM-store-bound by design.

constexpr int D    = 512;
constexpr int KTOT = 121;
constexpr int KP   = 128;   // padded k for phase-2 B
constexpr float TAU = 0.07f;

constexpr int GB[5]  = {0, 2, 17, 57, 97};   // group base row in concat [121] layout
constexpr int GK[5]  = {2, 15, 40, 40, 24};  // prototypes per group
constexpr int GD2[5] = {1, 3, 5, 5, 4};      // second attribute cardinality
constexpr int GNA[5] = {1, 2, 2, 2, 2};      // number of attributes
constexpr int KS0[5] = {0, 0, 0, 1, 3};      // first live 32-wide kstep of group
constexpr int KS1[5] = {1, 1, 2, 4, 4};      // one past last live kstep

using f32x4 = __attribute__((ext_vector_type(4))) float;
using s16x8 = __attribute__((ext_vector_type(8))) short;

__device__ __forceinline__ const float* pick(int k,
    const float* P0, const float* P1, const float* P2, const float* P3, const float* P4,
    int* kl) {
  if (k < 2)  { *kl = k;      return P0; }
  if (k < 17) { *kl = k - 2;  return P1; }
  if (k < 57) { *kl = k - 17; return P2; }
  if (k < 97) { *kl = k - 57; return P3; }
  *kl = k - 97; return P4;
}

__device__ __forceinline__ short f2bf(float f) {
  __hip_bfloat16 h = __float2bfloat16(f);   // RTNE
  return *reinterpret_cast<short*>(&h);
}

// ---- prep 1: inverse norms of the 121 prototype rows --------------------
__global__ void prep_norms(const float* __restrict__ P0, const float* __restrict__ P1,
                           const float* __restrict__ P2, const float* __restrict__ P3,
                           const float* __restrict__ P4, float* __restrict__ invn) {
  int k = blockIdx.x;  // 0..120
  int kl; const float* P = pick(k, P0, P1, P2, P3, P4, &kl);
  const float* row = P + (size_t)kl * D;
  float s = 0.f;
  for (int d = threadIdx.x; d < D; d += 64) { float v = row[d]; s += v * v; }
  #pragma unroll
  for (int m = 1; m < 64; m <<= 1) s += __shfl_xor(s, m);
  if (threadIdx.x == 0) invn[k] = 1.f / (sqrtf(s) + 1e-6f);
}

// ---- prep 2: pnb[c][k] = bf16(Pn[c][k]), rows 121..127 zero -------------
__global__ void prep_pnb(const float* __restrict__ P0, const float* __restrict__ P1,
                         const float* __restrict__ P2, const float* __restrict__ P3,
                         const float* __restrict__ P4, const float* __restrict__ invn,
                         unsigned short* __restrict__ pnb) {
  int idx = blockIdx.x * 256 + threadIdx.x;  // 128*512 = 65536
  int c = idx >> 9, k = idx & (D - 1);
  float v = 0.f;
  if (c < KTOT) {
    int kl; const float* P = pick(c, P0, P1, P2, P3, P4, &kl);
    v = P[(size_t)kl * D + k] * invn[c];
  }
  pnb[idx] = (unsigned short)f2bf(v);
}

// ---- prep 3: mptb[gd][kp] = bf16 block-diagonal (A@P/rowsum)^T ----------
// gd = g*512 + d (output column), kp = global k. Nonzero only for
// kp in [GB[g], GB[g]+GK[g]); value = M'_g[kp-GB[g]][d].
__global__ void prep_mpt(const float* __restrict__ P0, const float* __restrict__ P1,
                         const float* __restrict__ P2, const float* __restrict__ P3,
                         const float* __restrict__ P4, unsigned short* __restrict__ mptb) {
  int idx = blockIdx.x * 256 + threadIdx.x;  // 2560*128 = 327680
  int gd = idx >> 7, kp = idx & (KP - 1);
  int g = gd >> 9, d = gd & (D - 1);
  float v = 0.f;
  if (kp >= GB[g] && kp < GB[g] + GK[g]) {
    int kl = kp - GB[g];
    const float* P = (g == 0) ? P0 : (g == 1) ? P1 : (g == 2) ? P2 : (g == 3) ? P3 : P4;
    int d2 = GD2[g], na = GNA[g], K = GK[g];
    int a1 = kl / d2, a2 = kl % d2;
    float s = 0.f, m = 0.f;
    for (int j = 0; j < K; j++) {
      float aff;
      if (na == 1) {
        aff = (j == kl) ? 1.f : 0.f;
      } else {
        int b1 = j / d2, b2 = j % d2;
        aff = 0.5f * (float)((a1 == b1) + (a2 == b2));
      }
      s += aff;
      m += aff * P[(size_t)j * D + d];
    }
    v = m / (s + 1e-6f);
  }
  mptb[idx] = (unsigned short)f2bf(v);
}

// ---- main fused kernel --------------------------------------------------
__global__ __launch_bounds__(512, 4) void fused_main(
    const float* __restrict__ x, const unsigned short* __restrict__ pnb,
    const unsigned short* __restrict__ mptb, float* __restrict__ out) {
  __shared__ float lred[KP][65];   // [k][row], pad-65; rows 121..127 end up 0
  __shared__ float xsqs[64];       // ||x||^2 per block-row

  const int tid  = threadIdx.x;
  const int lane = tid & 63;
  const int w    = __builtin_amdgcn_readfirstlane(tid >> 6);
  const int r0   = blockIdx.x * 64;

  const int wr = (w & 3) << 4;   // wave's 16-row slab (block-local)
  const int ch = w >> 2;         // phase-1 column half / phase-2 col parity
  const int ko = (lane >> 4) << 3;

  // ---- phase 1: 16x64 logit tile via MFMA, K = 512 ----
  {
    const int arow = wr + (lane & 15);
    const float* xrow = x + (size_t)(r0 + arow) * D + ko;

    f32x4 acc[4];
    #pragma unroll
    for (int t = 0; t < 4; ++t) acc[t] = (f32x4){0.f, 0.f, 0.f, 0.f};
    float xsq = 0.f;

    #pragma unroll 4
    for (int s = 0; s < 16; ++s) {
      float4 a0 = *(const float4*)(xrow + s * 32);
      float4 a1 = *(const float4*)(xrow + s * 32 + 4);
      xsq += a0.x * a0.x + a0.y * a0.y + a0.z * a0.z + a0.w * a0.w
           + a1.x * a1.x + a1.y * a1.y + a1.z * a1.z + a1.w * a1.w;
      s16x8 af;
      af[0] = f2bf(a0.x); af[1] = f2bf(a0.y); af[2] = f2bf(a0.z); af[3] = f2bf(a0.w);
      af[4] = f2bf(a1.x); af[5] = f2bf(a1.y); af[6] = f2bf(a1.z); af[7] = f2bf(a1.w);
      #pragma unroll
      for (int t = 0; t < 4; ++t) {
        const int col = (ch << 6) + (t << 4) + (lane & 15);
        s16x8 bfv = *(const s16x8*)(pnb + (size_t)col * D + s * 32 + ko);
        acc[t] = __builtin_amdgcn_mfma_f32_16x16x32_bf16(af, bfv, acc[t], 0, 0, 0);
      }
    }

    // ||x||^2: lanes {l, l^16, l^32, l^48} share the same A-row
    xsq += __shfl_xor(xsq, 16);
    xsq += __shfl_xor(xsq, 32);
    if (w < 4 && lane < 16) xsqs[wr + lane] = xsq;

    // dump C-frags: col = lane&15, row = (lane>>4)*4 + j
    const int drow = wr + ((lane >> 4) << 2);
    #pragma unroll
    for (int t = 0; t < 4; ++t) {
      const int col = (ch << 6) + (t << 4) + (lane & 15);
      #pragma unroll
      for (int j = 0; j < 4; ++j) lred[col][drow + j] = acc[t][j];
    }
  }
  __syncthreads();

  // ---- softmax per group (wave g handles group g; lane = row), 3-pass ----
  if (w < 5) {
    const int g = w;
    const float scale = 1.f / ((sqrtf(xsqs[lane]) + 1e-6f) * TAU);
    float mx = -1e30f;
    for (int kk = 0; kk < GK[g]; ++kk)
      mx = fmaxf(mx, lred[GB[g] + kk][lane]);
    float E = 0.f;
    for (int kk = 0; kk < GK[g]; ++kk) {
      float e = __expf((lred[GB[g] + kk][lane] - mx) * scale);
      lred[GB[g] + kk][lane] = e;
      E += e;
    }
    const float inv = 1.f / E;
    for (int kk = 0; kk < GK[g]; ++kk) lred[GB[g] + kk][lane] *= inv;
  }
  __syncthreads();

  // ---- phase 2: out[64 x 2560] = C[64 x 128] @ Btilde[128 x 2560] ----
  // Wave: row-tile (w&3), col parity (w>>2). A-frags built once (dense k,
  // rows 121..127 of lred are 0), reused for 80 col-tiles.
  {
    const int ar = wr + (lane & 15);
    s16x8 af2[4];
    #pragma unroll
    for (int s = 0; s < 4; ++s) {
      const int kbase = s * 32 + ko;
      s16x8 f;
      #pragma unroll
      for (int j = 0; j < 8; ++j) f[j] = f2bf(lred[kbase + j][ar]);
      af2[s] = f;
    }

    const int orow0 = r0 + wr + ((lane >> 4) << 2);
    float* obase = out + (size_t)orow0 * (5 * D) + (lane & 15);

    #pragma unroll 1
    for (int ct = 0; ct < 80; ++ct) {
      const int gd0 = (((ct << 1) | ch) << 4);
      const int g   = gd0 >> 9;
      f32x4 acc2 = (f32x4){0.f, 0.f, 0.f, 0.f};
      const int s1 = KS1[g];
      #pragma unroll 1
      for (int s = KS0[g]; s < s1; ++s) {
        s16x8 bfv = *(const s16x8*)(mptb + (size_t)(gd0 + (lane & 15)) * KP + s * 32 + ko);
        acc2 = __builtin_amdgcn_mfma_f32_16x16x32_bf16(af2[s], bfv, acc2, 0, 0, 0);
      }
      float* op = obase + gd0;
      op[0]            = acc2[0];
      op[5 * D]        = acc2[1];
      op[2 * (5 * D)]  = acc2[2];
      op[3 * (5 * D)]  = acc2[3];
    }
  }
}

extern "C" void kernel_launch(void* const* d_in, const int* in_sizes, int n_in,
                              void* d_out, int out_size, void* d_ws, size_t ws_size,
                              hipStream_t stream) {
  const float* x  = (const float*)d_in[0];
  const float* P0 = (const float*)d_in[1];  // gender [2,512]
  const float* P1 = (const float*)d_in[2];  // hair   [15,512]
  const float* P2 = (const float*)d_in[3];  // top    [40,512]
  const float* P3 = (const float*)d_in[4];  // pants  [40,512]
  const float* P4 = (const float*)d_in[5];  // shoes  [24,512]
  float* out = (float*)d_out;

  unsigned short* pnb  = (unsigned short*)d_ws;        // 128*512  u16 = 128 KiB
  unsigned short* mptb = pnb + 128 * 512;              // 2560*128 u16 = 640 KiB
  float* invn = (float*)(mptb + 2560 * 128);           // 121 floats

  prep_norms<<<dim3(121), dim3(64), 0, stream>>>(P0, P1, P2, P3, P4, invn);
  prep_pnb<<<dim3(256), dim3(256), 0, stream>>>(P0, P1, P2, P3, P4, invn, pnb);
  prep_mpt<<<dim3(1280), dim3(256), 0, stream>>>(P0, P1, P2, P3, P4, mptb);
  fused_main<<<dim3(512), dim3(512), 0, stream>>>(x, pnb, mptb, out);
}

// Round 6
// 156.479 us; speedup vs baseline: 6.3095x; 6.3095x over previous
//
#include <hip/hip_runtime.h>
#include <hip/hip_bf16.h>
#include <math.h>

// CerberusSemanticIDBranch — fused prototype-softmax-affinity kernel for MI355X.
//
// out[r,g,:] = (e_g @ M'_g) / sum(e_g),  e_k = exp(l_k - max_g),
// l_k = (x_r . Pn_k) / ((||x_r||+1e-6) * tau),  Pn_k = P_k/(||P_k||+1e-6),
// M'_g = A_g @ P_g / (rowsum(A_g)+1e-6)   (rowsum(A) is constant per group).
//
// Round 6: same as round 5 (both matmuls on bf16 MFMA; phase-2 B = 128x2560
// block-diagonal bf16 so zeros mask cross-group terms) but phase 2 is
// restructured as template<G> with constexpr kstep bounds: every af2[s]
// index is compile-time, so the A-fragments stay in VGPRs. Round 5 indexed
// af2[] with a runtime bound -> scratch allocation -> 5x regression
// (rule: runtime-indexed ext_vector arrays go to local memory).

constexpr int D    = 512;
constexpr int KTOT = 121;
constexpr int KP   = 128;   // padded k for phase-2 B
constexpr float TAU = 0.07f;

constexpr int GB[5]  = {0, 2, 17, 57, 97};   // group base row in concat [121] layout
constexpr int GK[5]  = {2, 15, 40, 40, 24};  // prototypes per group
constexpr int GD2[5] = {1, 3, 5, 5, 4};      // second attribute cardinality
constexpr int GNA[5] = {1, 2, 2, 2, 2};      // number of attributes
constexpr int KS0[5] = {0, 0, 0, 1, 3};      // first live 32-wide kstep of group
constexpr int KS1[5] = {1, 1, 2, 4, 4};      // one past last live kstep

using f32x4 = __attribute__((ext_vector_type(4))) float;
using s16x8 = __attribute__((ext_vector_type(8))) short;

__device__ __forceinline__ const float* pick(int k,
    const float* P0, const float* P1, const float* P2, const float* P3, const float* P4,
    int* kl) {
  if (k < 2)  { *kl = k;      return P0; }
  if (k < 17) { *kl = k - 2;  return P1; }
  if (k < 57) { *kl = k - 17; return P2; }
  if (k < 97) { *kl = k - 57; return P3; }
  *kl = k - 97; return P4;
}

__device__ __forceinline__ short f2bf(float f) {
  __hip_bfloat16 h = __float2bfloat16(f);   // RTNE
  return *reinterpret_cast<short*>(&h);
}

// ---- prep 1: inverse norms of the 121 prototype rows --------------------
__global__ void prep_norms(const float* __restrict__ P0, const float* __restrict__ P1,
                           const float* __restrict__ P2, const float* __restrict__ P3,
                           const float* __restrict__ P4, float* __restrict__ invn) {
  int k = blockIdx.x;  // 0..120
  int kl; const float* P = pick(k, P0, P1, P2, P3, P4, &kl);
  const float* row = P + (size_t)kl * D;
  float s = 0.f;
  for (int d = threadIdx.x; d < D; d += 64) { float v = row[d]; s += v * v; }
  #pragma unroll
  for (int m = 1; m < 64; m <<= 1) s += __shfl_xor(s, m);
  if (threadIdx.x == 0) invn[k] = 1.f / (sqrtf(s) + 1e-6f);
}

// ---- prep 2: pnb[c][k] = bf16(Pn[c][k]), rows 121..127 zero -------------
__global__ void prep_pnb(const float* __restrict__ P0, const float* __restrict__ P1,
                         const float* __restrict__ P2, const float* __restrict__ P3,
                         const float* __restrict__ P4, const float* __restrict__ invn,
                         unsigned short* __restrict__ pnb) {
  int idx = blockIdx.x * 256 + threadIdx.x;  // 128*512 = 65536
  int c = idx >> 9, k = idx & (D - 1);
  float v = 0.f;
  if (c < KTOT) {
    int kl; const float* P = pick(c, P0, P1, P2, P3, P4, &kl);
    v = P[(size_t)kl * D + k] * invn[c];
  }
  pnb[idx] = (unsigned short)f2bf(v);
}

// ---- prep 3: mptb[gd][kp] = bf16 block-diagonal (A@P/rowsum)^T ----------
// gd = g*512 + d (output column), kp = global k. Nonzero only for
// kp in [GB[g], GB[g]+GK[g]); value = M'_g[kp-GB[g]][d].
__global__ void prep_mpt(const float* __restrict__ P0, const float* __restrict__ P1,
                         const float* __restrict__ P2, const float* __restrict__ P3,
                         const float* __restrict__ P4, unsigned short* __restrict__ mptb) {
  int idx = blockIdx.x * 256 + threadIdx.x;  // 2560*128 = 327680
  int gd = idx >> 7, kp = idx & (KP - 1);
  int g = gd >> 9, d = gd & (D - 1);
  float v = 0.f;
  if (kp >= GB[g] && kp < GB[g] + GK[g]) {
    int kl = kp - GB[g];
    const float* P = (g == 0) ? P0 : (g == 1) ? P1 : (g == 2) ? P2 : (g == 3) ? P3 : P4;
    int d2 = GD2[g], na = GNA[g], K = GK[g];
    int a1 = kl / d2, a2 = kl % d2;
    float s = 0.f, m = 0.f;
    for (int j = 0; j < K; j++) {
      float aff;
      if (na == 1) {
        aff = (j == kl) ? 1.f : 0.f;
      } else {
        int b1 = j / d2, b2 = j % d2;
        aff = 0.5f * (float)((a1 == b1) + (a2 == b2));
      }
      s += aff;
      m += aff * P[(size_t)j * D + d];
    }
    v = m / (s + 1e-6f);
  }
  mptb[idx] = (unsigned short)f2bf(v);
}

// ---- phase 2 per-group body: all fragment indices compile-time ----------
template <int G>
__device__ __forceinline__ void phase2_group(
    const s16x8 (&af2)[4], const unsigned short* __restrict__ mptb,
    float* __restrict__ obase, int ch, int lane15, int ko) {
  // group G owns output columns [G*512, G*512+512) -> 32 col-tiles of 16;
  // this wave takes the 16 tiles with parity ch.
  #pragma unroll 1
  for (int tt = 0; tt < 16; ++tt) {
    const int gd0 = G * 512 + (((tt << 1) | ch) << 4);
    f32x4 acc2 = (f32x4){0.f, 0.f, 0.f, 0.f};
    const unsigned short* bp = mptb + (size_t)(gd0 + lane15) * KP + ko;
    #pragma unroll
    for (int s = KS0[G]; s < KS1[G]; ++s) {   // constexpr bounds -> af2[s] static
      s16x8 bfv = *(const s16x8*)(bp + s * 32);
      acc2 = __builtin_amdgcn_mfma_f32_16x16x32_bf16(af2[s], bfv, acc2, 0, 0, 0);
    }
    float* op = obase + gd0;
    op[0]            = acc2[0];
    op[5 * D]        = acc2[1];
    op[2 * (5 * D)]  = acc2[2];
    op[3 * (5 * D)]  = acc2[3];
  }
}

// ---- main fused kernel --------------------------------------------------
__global__ __launch_bounds__(512, 4) void fused_main(
    const float* __restrict__ x, const unsigned short* __restrict__ pnb,
    const unsigned short* __restrict__ mptb, float* __restrict__ out) {
  __shared__ float lred[KP][65];   // [k][row], pad-65; rows 121..127 end up 0
  __shared__ float xsqs[64];       // ||x||^2 per block-row

  const int tid  = threadIdx.x;
  const int lane = tid & 63;
  const int w    = __builtin_amdgcn_readfirstlane(tid >> 6);
  const int r0   = blockIdx.x * 64;

  const int wr = (w & 3) << 4;   // wave's 16-row slab (block-local)
  const int ch = w >> 2;         // phase-1 column half / phase-2 col parity
  const int ko = (lane >> 4) << 3;

  // ---- phase 1: 16x64 logit tile via MFMA, K = 512 ----
  {
    const int arow = wr + (lane & 15);
    const float* xrow = x + (size_t)(r0 + arow) * D + ko;

    f32x4 acc[4];
    #pragma unroll
    for (int t = 0; t < 4; ++t) acc[t] = (f32x4){0.f, 0.f, 0.f, 0.f};
    float xsq = 0.f;

    #pragma unroll 4
    for (int s = 0; s < 16; ++s) {
      float4 a0 = *(const float4*)(xrow + s * 32);
      float4 a1 = *(const float4*)(xrow + s * 32 + 4);
      xsq += a0.x * a0.x + a0.y * a0.y + a0.z * a0.z + a0.w * a0.w
           + a1.x * a1.x + a1.y * a1.y + a1.z * a1.z + a1.w * a1.w;
      s16x8 af;
      af[0] = f2bf(a0.x); af[1] = f2bf(a0.y); af[2] = f2bf(a0.z); af[3] = f2bf(a0.w);
      af[4] = f2bf(a1.x); af[5] = f2bf(a1.y); af[6] = f2bf(a1.z); af[7] = f2bf(a1.w);
      #pragma unroll
      for (int t = 0; t < 4; ++t) {
        const int col = (ch << 6) + (t << 4) + (lane & 15);
        s16x8 bfv = *(const s16x8*)(pnb + (size_t)col * D + s * 32 + ko);
        acc[t] = __builtin_amdgcn_mfma_f32_16x16x32_bf16(af, bfv, acc[t], 0, 0, 0);
      }
    }

    // ||x||^2: lanes {l, l^16, l^32, l^48} share the same A-row
    xsq += __shfl_xor(xsq, 16);
    xsq += __shfl_xor(xsq, 32);
    if (w < 4 && lane < 16) xsqs[wr + lane] = xsq;

    // dump C-frags: col = lane&15, row = (lane>>4)*4 + j
    const int drow = wr + ((lane >> 4) << 2);
    #pragma unroll
    for (int t = 0; t < 4; ++t) {
      const int col = (ch << 6) + (t << 4) + (lane & 15);
      #pragma unroll
      for (int j = 0; j < 4; ++j) lred[col][drow + j] = acc[t][j];
    }
  }
  __syncthreads();

  // ---- softmax per group (wave g handles group g; lane = row), 3-pass ----
  if (w < 5) {
    const int g = w;
    const float scale = 1.f / ((sqrtf(xsqs[lane]) + 1e-6f) * TAU);
    float mx = -1e30f;
    for (int kk = 0; kk < GK[g]; ++kk)
      mx = fmaxf(mx, lred[GB[g] + kk][lane]);
    float E = 0.f;
    for (int kk = 0; kk < GK[g]; ++kk) {
      float e = __expf((lred[GB[g] + kk][lane] - mx) * scale);
      lred[GB[g] + kk][lane] = e;
      E += e;
    }
    const float inv = 1.f / E;
    for (int kk = 0; kk < GK[g]; ++kk) lred[GB[g] + kk][lane] *= inv;
  }
  __syncthreads();

  // ---- phase 2: out[64 x 2560] = C[64 x 128] @ Btilde[128 x 2560] ----
  {
    const int ar = wr + (lane & 15);
    s16x8 af2[4];
    #pragma unroll
    for (int s = 0; s < 4; ++s) {
      const int kbase = s * 32 + ko;
      s16x8 f;
      #pragma unroll
      for (int j = 0; j < 8; ++j) f[j] = f2bf(lred[kbase + j][ar]);
      af2[s] = f;
    }

    const int orow0 = r0 + wr + ((lane >> 4) << 2);
    float* obase = out + (size_t)orow0 * (5 * D) + (lane & 15);
    const int lane15 = lane & 15;

    phase2_group<0>(af2, mptb, obase, ch, lane15, ko);
    phase2_group<1>(af2, mptb, obase, ch, lane15, ko);
    phase2_group<2>(af2, mptb, obase, ch, lane15, ko);
    phase2_group<3>(af2, mptb, obase, ch, lane15, ko);
    phase2_group<4>(af2, mptb, obase, ch, lane15, ko);
  }
}

extern "C" void kernel_launch(void* const* d_in, const int* in_sizes, int n_in,
                              void* d_out, int out_size, void* d_ws, size_t ws_size,
                              hipStream_t stream) {
  const float* x  = (const float*)d_in[0];
  const float* P0 = (const float*)d_in[1];  // gender [2,512]
  const float* P1 = (const float*)d_in[2];  // hair   [15,512]
  const float* P2 = (const float*)d_in[3];  // top    [40,512]
  const float* P3 = (const float*)d_in[4];  // pants  [40,512]
  const float* P4 = (const float*)d_in[5];  // shoes  [24,512]
  float* out = (float*)d_out;

  unsigned short* pnb  = (unsigned short*)d_ws;        // 128*512  u16 = 128 KiB
  unsigned short* mptb = pnb + 128 * 512;              // 2560*128 u16 = 640 KiB
  float* invn = (float*)(mptb + 2560 * 128);           // 121 floats

  prep_norms<<<dim3(121), dim3(64), 0, stream>>>(P0, P1, P2, P3, P4, invn);
  prep_pnb<<<dim3(256), dim3(256), 0, stream>>>(P0, P1, P2, P3, P4, invn, pnb);
  prep_mpt<<<dim3(1280), dim3(256), 0, stream>>>(P0, P1, P2, P3, P4, mptb);
  fused_main<<<dim3(512), dim3(512), 0, stream>>>(x, pnb, mptb, out);
}